// Round 5
// baseline (380.482 us; speedup 1.0000x reference)
//
#include <hip/hip_runtime.h>
#include <hip/hip_cooperative_groups.h>
namespace cg = cooperative_groups;

#define NN 10000
#define NE 640000
#define DIM 128
#define HNB 64                        // hist/scatter blocks in mega kernel
#define HEPB 10000                    // edges per hist block (64*10000 = NE)
#define FCN 32                        // nodes per fc block
#define FCB ((NN + FCN - 1) / FCN)    // 313 fc blocks
#define DEGCAP 512

static __device__ __forceinline__ unsigned short f2bf(float f) {
    unsigned u = __float_as_uint(f);
    unsigned r = (u + 0x7FFFu + ((u >> 16) & 1u)) >> 16;   // RNE
    return (unsigned short)r;
}
static __device__ __forceinline__ float bfhi(unsigned u) { return __uint_as_float(u & 0xFFFF0000u); }
static __device__ __forceinline__ float bflo(unsigned u) { return __uint_as_float(u << 16); }

// ===========================================================================
// MEGA: A0 transpose | A1 hist+fc | A2 colscan | A3 scan | A4 scatter | A5 agg
// ===========================================================================
__global__ __launch_bounds__(256, 4) void mega_kernel(
    const float* __restrict__ h, const int* __restrict__ src,
    const int* __restrict__ dst, const float* __restrict__ W,
    const float* __restrict__ Wa, float* __restrict__ out,
    unsigned short* __restrict__ zb, float* __restrict__ e,
    int* __restrict__ cnt, int* __restrict__ offs, float* __restrict__ Wt,
    int* __restrict__ bh, int* __restrict__ esrc)
{
    __shared__ int smem[10240];                    // 40 KB, re-purposed per phase
    cg::grid_group grid = cg::this_grid();
    const int bid = blockIdx.x, t = threadIdx.x, nb = gridDim.x;

    // ---- A0: Wt[k][j] = W[j][k]  (last 64 blocks, 1 elem/thread) ----
    if (bid >= nb - 64) {
        int idx = (bid - (nb - 64)) * 256 + t;     // 0..16383
        Wt[(idx & 127) * DIM + (idx >> 7)] = W[idx];
    }
    grid.sync();

    // ---- A1: hist (blocks 0..63)  ||  fc (blocks 64..376) ----
    if (bid < HNB) {
        int* lh = smem;
        for (int v = t; v < NN; v += 256) lh[v] = 0;
        __syncthreads();
        const int4* d4 = (const int4*)(dst + bid * HEPB);
        for (int i = t; i < HEPB / 4; i += 256) {
            int4 d = d4[i];
            atomicAdd(&lh[d.x], 1); atomicAdd(&lh[d.y], 1);
            atomicAdd(&lh[d.z], 1); atomicAdd(&lh[d.w], 1);
        }
        __syncthreads();
        for (int v = t; v < NN; v += 256) bh[(size_t)bid * NN + v] = lh[v];
    } else if (bid < HNB + FCB) {
        float* hs = (float*)smem;                  // [FCN][DIM] = 16 KB
        const int jl = t & 31, jq = jl * 4, ng = t >> 5;
        const int i0 = (bid - HNB) * FCN;
        const float4* h4 = (const float4*)h;
        float4* hs4 = (float4*)hs;
        for (int u = t; u < FCN * 32; u += 256) {
            int row = u >> 5, gi = i0 + row;
            hs4[u] = (gi < NN) ? h4[(size_t)gi * 32 + (u & 31)]
                               : make_float4(0.f, 0.f, 0.f, 0.f);
        }
        __syncthreads();
        float acc[4][4] = {};
        for (int k = 0; k < DIM; k += 4) {
            float4 wv[4];
            #pragma unroll
            for (int kk = 0; kk < 4; ++kk)
                wv[kk] = *(const float4*)&Wt[(k + kk) * DIM + jq];
            const float* wf = (const float*)wv;
            #pragma unroll
            for (int m = 0; m < 4; ++m) {
                float4 hv = *(const float4*)&hs[(4 * ng + m) * DIM + k];
                float hvf[4] = {hv.x, hv.y, hv.z, hv.w};
                #pragma unroll
                for (int kk = 0; kk < 4; ++kk)
                    #pragma unroll
                    for (int jm = 0; jm < 4; ++jm)
                        acc[m][jm] += hvf[kk] * wf[kk * 4 + jm];
            }
        }
        const float a0 = Wa[jq], a1 = Wa[jq + 1], a2 = Wa[jq + 2], a3 = Wa[jq + 3];
        #pragma unroll
        for (int m = 0; m < 4; ++m) {
            int gi = i0 + 4 * ng + m;
            float ep = acc[m][0] * a0 + acc[m][1] * a1 + acc[m][2] * a2 + acc[m][3] * a3;
            #pragma unroll
            for (int o = 16; o > 0; o >>= 1) ep += __shfl_xor(ep, o, 64);
            if (gi < NN) {
                ushort4 zo;
                zo.x = f2bf(acc[m][0]); zo.y = f2bf(acc[m][1]);
                zo.z = f2bf(acc[m][2]); zo.w = f2bf(acc[m][3]);
                *(ushort4*)&zb[(size_t)gi * DIM + jq] = zo;
                if (jl == 0) e[gi] = ep;
            }
        }
    }
    grid.sync();

    // ---- A2: column scan of bh -> per-block bases (in place) + cnt ----
    {
        int v = bid * 256 + t;
        if (v < NN) {
            int run = 0;
            #pragma unroll 8
            for (int b = 0; b < HNB; ++b) {
                int c = bh[(size_t)b * NN + v];
                bh[(size_t)b * NN + v] = run;
                run += c;
            }
            cnt[v] = run;
        }
    }
    grid.sync();

    // ---- A3: exclusive scan cnt -> offs (block 0, 256 thr x 40 nodes) ----
    if (bid == 0) {
        constexpr int C = 40;
        const int base = t * C;
        int s = 0;
        for (int j = 0; j < C; ++j) {
            int idx = base + j;
            if (idx < NN) s += cnt[idx];
        }
        const int lane = t & 63, wid = t >> 6;
        int x = s;
        #pragma unroll
        for (int o = 1; o <= 32; o <<= 1) {
            int y = __shfl_up(x, o, 64);
            if (lane >= o) x += y;
        }
        if (lane == 63) smem[wid] = x;
        __syncthreads();
        if (t == 0) { smem[1] += smem[0]; smem[2] += smem[1]; smem[3] += smem[2]; }
        __syncthreads();
        int run = (wid ? smem[wid - 1] : 0) + (x - s);
        for (int j = 0; j < C; ++j) {
            int idx = base + j;
            if (idx < NN) { offs[idx] = run; run += cnt[idx]; }
        }
        if (t == 255) offs[NN] = run;
    }
    grid.sync();

    // ---- A4: LDS-ranked scatter (blocks 0..63) ----
    if (bid < HNB) {
        int* lh = smem;
        for (int v = t; v < NN; v += 256) lh[v] = 0;
        __syncthreads();
        const int4* d4 = (const int4*)(dst + bid * HEPB);
        const int4* s4 = (const int4*)(src + bid * HEPB);
        const int* brow = bh + (size_t)bid * NN;
        for (int i = t; i < HEPB / 4; i += 256) {
            int4 d = d4[i]; int4 s = s4[i];
            int lp;
            lp = atomicAdd(&lh[d.x], 1); esrc[offs[d.x] + brow[d.x] + lp] = s.x;
            lp = atomicAdd(&lh[d.y], 1); esrc[offs[d.y] + brow[d.y] + lp] = s.y;
            lp = atomicAdd(&lh[d.z], 1); esrc[offs[d.z] + brow[d.z] + lp] = s.z;
            lp = atomicAdd(&lh[d.w], 1); esrc[offs[d.w] + brow[d.w] + lp] = s.w;
        }
    }
    grid.sync();

    // ---- A5: softmax + aggregate, one wave per node, grid-stride ----
    {
        const int lane = t & 63, w = t >> 6;
        int*   es = smem + w * DEGCAP;                         // 4 x 512 ints
        float* ew = (float*)(smem + 4 * DEGCAP + w * DEGCAP);  // 4 x 512 floats
        const unsigned* zb32 = (const unsigned*)zb;
        for (int v = bid * 4 + w; v < NN; v += nb * 4) {
            const int beg = offs[v], end = offs[v + 1];
            const int deg = end - beg;
            float rx, ry;
            if (deg <= DEGCAP) {
                float lm = -3.4e38f;
                for (int i = lane; i < deg; i += 64) {
                    int s = esrc[beg + i];
                    es[i] = s;
                    lm = fmaxf(lm, e[s]);
                }
                #pragma unroll
                for (int o = 32; o > 0; o >>= 1) lm = fmaxf(lm, __shfl_xor(lm, o, 64));
                float ls = 0.f;
                for (int i = lane; i < deg; i += 64) {
                    float wv = __expf(e[es[i]] - lm);
                    ew[i] = wv; ls += wv;
                }
                #pragma unroll
                for (int o = 32; o > 0; o >>= 1) ls += __shfl_xor(ls, o, 64);
                const float inv = (ls > 0.f) ? (1.f / ls) : 0.f;
                float a0 = 0.f, a1 = 0.f, a2 = 0.f, a3 = 0.f;
                int i = 0;
                for (; i + 1 < deg; i += 2) {
                    unsigned u0 = zb32[(size_t)es[i]     * 64 + lane];
                    unsigned u1 = zb32[(size_t)es[i + 1] * 64 + lane];
                    float w0 = ew[i], w1 = ew[i + 1];
                    a0 += w0 * bflo(u0); a1 += w0 * bfhi(u0);
                    a2 += w1 * bflo(u1); a3 += w1 * bfhi(u1);
                }
                if (i < deg) {
                    unsigned u0 = zb32[(size_t)es[i] * 64 + lane];
                    a0 += ew[i] * bflo(u0); a1 += ew[i] * bfhi(u0);
                }
                rx = (a0 + a2) * inv; ry = (a1 + a3) * inv;
            } else {
                float lm = -3.4e38f;
                for (int i = beg + lane; i < end; i += 64) lm = fmaxf(lm, e[esrc[i]]);
                #pragma unroll
                for (int o = 32; o > 0; o >>= 1) lm = fmaxf(lm, __shfl_xor(lm, o, 64));
                float ls = 0.f;
                for (int i = beg + lane; i < end; i += 64) ls += __expf(e[esrc[i]] - lm);
                #pragma unroll
                for (int o = 32; o > 0; o >>= 1) ls += __shfl_xor(ls, o, 64);
                const float inv = (ls > 0.f) ? (1.f / ls) : 0.f;
                float a0 = 0.f, a1 = 0.f;
                for (int i = beg; i < end; ++i) {
                    int s = esrc[i];
                    float wv = __expf(e[s] - lm);
                    unsigned u = zb32[(size_t)s * 64 + lane];
                    a0 += wv * bflo(u); a1 += wv * bfhi(u);
                }
                rx = a0 * inv; ry = a1 * inv;
            }
            float2 r; r.x = rx; r.y = ry;
            *(float2*)&out[(size_t)v * DIM + 2 * lane] = r;
        }
    }
}

// ===========================================================================
// Fallback path (R4-proven separate kernels), used if cooperative launch fails
// ===========================================================================
#define NB 125
#define EPB 5120

__global__ __launch_bounds__(256) void hist2T_kernel(
    const int* __restrict__ dst, int* __restrict__ bh,
    const float* __restrict__ W, float* __restrict__ Wt)
{
    __shared__ int lh[NN];
    const int b = blockIdx.x, t = threadIdx.x;
    for (int v = t; v < NN; v += 256) lh[v] = 0;
    for (int u = t; u < 132; u += 256) {
        int idx = b * 132 + u;
        if (idx < DIM * DIM) Wt[(idx & 127) * DIM + (idx >> 7)] = W[idx];
    }
    __syncthreads();
    const int4* d4 = (const int4*)(dst + b * EPB);
    for (int i = t; i < EPB / 4; i += 256) {
        int4 d = d4[i];
        atomicAdd(&lh[d.x], 1); atomicAdd(&lh[d.y], 1);
        atomicAdd(&lh[d.z], 1); atomicAdd(&lh[d.w], 1);
    }
    __syncthreads();
    for (int v = t; v < NN; v += 256) bh[(size_t)b * NN + v] = lh[v];
}

__global__ __launch_bounds__(256) void fc3_kernel(
    const float* __restrict__ h, const float* __restrict__ Wt,
    const float* __restrict__ Wa, unsigned short* __restrict__ zb,
    float* __restrict__ e, int n)
{
    __shared__ float hs[FCN][DIM];
    const int t  = threadIdx.x;
    const int jl = t & 31, jq = jl * 4;
    const int ng = t >> 5;
    const int i0 = blockIdx.x * FCN;
    const float4* h4 = (const float4*)h;
    float4* hs4 = (float4*)hs;
    for (int u = t; u < FCN * 32; u += 256) {
        int row = u >> 5, gi = i0 + row;
        hs4[u] = (gi < n) ? h4[(size_t)gi * 32 + (u & 31)]
                          : make_float4(0.f, 0.f, 0.f, 0.f);
    }
    __syncthreads();
    float acc[4][4] = {};
    for (int k = 0; k < DIM; k += 4) {
        float4 wv[4];
        #pragma unroll
        for (int kk = 0; kk < 4; ++kk)
            wv[kk] = *(const float4*)&Wt[(k + kk) * DIM + jq];
        const float* wf = (const float*)wv;
        #pragma unroll
        for (int m = 0; m < 4; ++m) {
            float4 hv = *(const float4*)&hs[4 * ng + m][k];
            float hvf[4] = {hv.x, hv.y, hv.z, hv.w};
            #pragma unroll
            for (int kk = 0; kk < 4; ++kk)
                #pragma unroll
                for (int jm = 0; jm < 4; ++jm)
                    acc[m][jm] += hvf[kk] * wf[kk * 4 + jm];
        }
    }
    const float a0 = Wa[jq], a1 = Wa[jq + 1], a2 = Wa[jq + 2], a3 = Wa[jq + 3];
    #pragma unroll
    for (int m = 0; m < 4; ++m) {
        int gi = i0 + 4 * ng + m;
        float ep = acc[m][0] * a0 + acc[m][1] * a1 + acc[m][2] * a2 + acc[m][3] * a3;
        #pragma unroll
        for (int o = 16; o > 0; o >>= 1) ep += __shfl_xor(ep, o, 64);
        if (gi < n) {
            ushort4 zo;
            zo.x = f2bf(acc[m][0]); zo.y = f2bf(acc[m][1]);
            zo.z = f2bf(acc[m][2]); zo.w = f2bf(acc[m][3]);
            *(ushort4*)&zb[(size_t)gi * DIM + jq] = zo;
            if (jl == 0) e[gi] = ep;
        }
    }
}

__global__ void colscan0_kernel(int* __restrict__ bh, int* __restrict__ cnt)
{
    int v = blockIdx.x * blockDim.x + threadIdx.x;
    if (v < NN) {
        int run = 0;
        #pragma unroll 5
        for (int b = 0; b < NB; ++b) {
            int c = bh[(size_t)b * NN + v];
            bh[(size_t)b * NN + v] = run;
            run += c;
        }
        cnt[v] = run;
    }
}

__global__ __launch_bounds__(1024) void scan_kernel(
    const int* __restrict__ cnt, int* __restrict__ offs, int n)
{
    __shared__ int wsum[16];
    const int t = threadIdx.x, lane = t & 63, wid = t >> 6;
    constexpr int C = 10;
    int loc[C];
    int base = t * C, s = 0;
    #pragma unroll
    for (int j = 0; j < C; ++j) {
        int idx = base + j;
        int v = (idx < n) ? cnt[idx] : 0;
        loc[j] = s; s += v;
    }
    int x = s;
    #pragma unroll
    for (int off = 1; off <= 32; off <<= 1) {
        int y = __shfl_up(x, off, 64);
        if (lane >= off) x += y;
    }
    if (lane == 63) wsum[wid] = x;
    __syncthreads();
    if (t < 16) {
        int w = wsum[t];
        #pragma unroll
        for (int off = 1; off <= 8; off <<= 1) {
            int y = __shfl_up(w, off, 64);
            if (t >= off) w += y;
        }
        wsum[t] = w;
    }
    __syncthreads();
    int wbase = (wid == 0) ? 0 : wsum[wid - 1];
    int excl = wbase + (x - s);
    #pragma unroll
    for (int j = 0; j < C; ++j) {
        int idx = base + j;
        if (idx < n) offs[idx] = excl + loc[j];
    }
    if (t == 0) offs[n] = wsum[15];
}

__global__ __launch_bounds__(256) void scatter2_kernel(
    const int* __restrict__ src, const int* __restrict__ dst,
    const int* __restrict__ base, const int* __restrict__ offs,
    int* __restrict__ esrc)
{
    __shared__ int lcur[NN];
    const int b = blockIdx.x, t = threadIdx.x;
    for (int v = t; v < NN; v += 256) lcur[v] = 0;
    __syncthreads();
    const int4* d4 = (const int4*)(dst + b * EPB);
    const int4* s4 = (const int4*)(src + b * EPB);
    const int* brow = base + (size_t)b * NN;
    for (int i = t; i < EPB / 4; i += 256) {
        int4 d = d4[i]; int4 s = s4[i];
        int lp;
        lp = atomicAdd(&lcur[d.x], 1); esrc[offs[d.x] + brow[d.x] + lp] = s.x;
        lp = atomicAdd(&lcur[d.y], 1); esrc[offs[d.y] + brow[d.y] + lp] = s.y;
        lp = atomicAdd(&lcur[d.z], 1); esrc[offs[d.z] + brow[d.z] + lp] = s.z;
        lp = atomicAdd(&lcur[d.w], 1); esrc[offs[d.w] + brow[d.w] + lp] = s.w;
    }
}

__global__ __launch_bounds__(64) void agg64_kernel(
    const int* __restrict__ offs, const int* __restrict__ esrc,
    const float* __restrict__ e, const unsigned* __restrict__ zb32,
    float* __restrict__ out)
{
    __shared__ int   es[DEGCAP];
    __shared__ float ew[DEGCAP];
    const int v = blockIdx.x, t = threadIdx.x;
    const int beg = offs[v], end = offs[v + 1];
    const int deg = end - beg;
    if (deg <= DEGCAP) {
        float lm = -3.4e38f;
        for (int i = t; i < deg; i += 64) {
            int s = esrc[beg + i];
            es[i] = s;
            lm = fmaxf(lm, e[s]);
        }
        #pragma unroll
        for (int o = 32; o > 0; o >>= 1) lm = fmaxf(lm, __shfl_xor(lm, o, 64));
        float ls = 0.f;
        for (int i = t; i < deg; i += 64) {
            float w = __expf(e[es[i]] - lm);
            ew[i] = w; ls += w;
        }
        #pragma unroll
        for (int o = 32; o > 0; o >>= 1) ls += __shfl_xor(ls, o, 64);
        const float inv = (ls > 0.f) ? (1.f / ls) : 0.f;
        __syncthreads();
        float a0 = 0.f, a1 = 0.f, a2 = 0.f, a3 = 0.f;
        int i = 0;
        for (; i + 1 < deg; i += 2) {
            unsigned u0 = zb32[(size_t)es[i]     * 64 + t];
            unsigned u1 = zb32[(size_t)es[i + 1] * 64 + t];
            float w0 = ew[i], w1 = ew[i + 1];
            a0 += w0 * bflo(u0); a1 += w0 * bfhi(u0);
            a2 += w1 * bflo(u1); a3 += w1 * bfhi(u1);
        }
        if (i < deg) {
            unsigned u = zb32[(size_t)es[i] * 64 + t];
            a0 += ew[i] * bflo(u); a1 += ew[i] * bfhi(u);
        }
        float2 r;
        r.x = (a0 + a2) * inv;
        r.y = (a1 + a3) * inv;
        *(float2*)&out[(size_t)v * DIM + 2 * t] = r;
    } else {
        float lm = -3.4e38f;
        for (int i = beg + t; i < end; i += 64) lm = fmaxf(lm, e[esrc[i]]);
        #pragma unroll
        for (int o = 32; o > 0; o >>= 1) lm = fmaxf(lm, __shfl_xor(lm, o, 64));
        float ls = 0.f;
        for (int i = beg + t; i < end; i += 64) ls += __expf(e[esrc[i]] - lm);
        #pragma unroll
        for (int o = 32; o > 0; o >>= 1) ls += __shfl_xor(ls, o, 64);
        const float inv = (ls > 0.f) ? (1.f / ls) : 0.f;
        float a0 = 0.f, a1 = 0.f;
        for (int i = beg; i < end; ++i) {
            int s = esrc[i];
            float w = __expf(e[s] - lm);
            unsigned u = zb32[(size_t)s * 64 + t];
            a0 += w * bflo(u); a1 += w * bfhi(u);
        }
        float2 r;
        r.x = a0 * inv;
        r.y = a1 * inv;
        *(float2*)&out[(size_t)v * DIM + 2 * t] = r;
    }
}

// ===========================================================================
extern "C" void kernel_launch(void* const* d_in, const int* in_sizes, int n_in,
                              void* d_out, int out_size, void* d_ws, size_t ws_size,
                              hipStream_t stream)
{
    const float* h     = (const float*)d_in[0];
    const int*   src   = (const int*)d_in[1];
    const int*   dst   = (const int*)d_in[2];
    const float* Wfc   = (const float*)d_in[3];
    const float* Wattn = (const float*)d_in[4];
    float* out = (float*)d_out;

    // workspace layout (sized for the larger of the two paths: NBmax = 125)
    unsigned short* zb   = (unsigned short*)d_ws;     // NN*DIM ushort (2.56 MB)
    float*          e    = (float*)(zb + (size_t)NN * DIM + 16);
    int*            cnt  = (int*)(e + 10016);
    int*            offs = cnt + 10016;
    float*          Wt   = (float*)(offs + 10016);    // 16,384 f32
    int*            bh   = (int*)(Wt + 16384);        // up to 125*NN int
    int*            esrc = bh + (size_t)125 * NN;     // NE int

    // cooperative mega-kernel: grid sized to guaranteed co-residency
    int maxb = 0;
    hipError_t qrc = hipOccupancyMaxActiveBlocksPerMultiprocessor(
        &maxb, (const void*)mega_kernel, 256, 0);
    int grid = (qrc == hipSuccess) ? maxb * 256 : 0;
    if (grid > 1024) grid = 1024;

    bool ok = false;
    if (grid >= HNB + FCB + 64) {                 // need 441+ blocks for phases
        void* args[] = { (void*)&h, (void*)&src, (void*)&dst, (void*)&Wfc,
                         (void*)&Wattn, (void*)&out, (void*)&zb, (void*)&e,
                         (void*)&cnt, (void*)&offs, (void*)&Wt, (void*)&bh,
                         (void*)&esrc };
        hipError_t rc = hipLaunchCooperativeKernel(
            (const void*)mega_kernel, dim3(grid), dim3(256), args, 0, stream);
        ok = (rc == hipSuccess);
    }

    if (!ok) {
        // fallback: proven 6-kernel path
        hist2T_kernel<<<NB, 256, 0, stream>>>(dst, bh, Wfc, Wt);
        fc3_kernel<<<(NN + FCN - 1) / FCN, 256, 0, stream>>>(h, Wt, Wattn, zb, e, NN);
        colscan0_kernel<<<(NN + 255) / 256, 256, 0, stream>>>(bh, cnt);
        scan_kernel<<<1, 1024, 0, stream>>>(cnt, offs, NN);
        scatter2_kernel<<<NB, 256, 0, stream>>>(src, dst, bh, offs, esrc);
        agg64_kernel<<<NN, 64, 0, stream>>>(offs, esrc, e, (const unsigned*)zb, out);
    }
}

// Round 6
// 95.465 us; speedup vs baseline: 3.9856x; 3.9856x over previous
//
#include <hip/hip_runtime.h>

#define NN 10000
#define NE 640000
#define DIM 128
#define HNB 64                        // hist/scatter blocks (== wavefront size!)
#define HEPB 10000                    // edges per hist block (64*10000 = NE)
#define FCN 64                        // nodes per fc block
#define FCB ((NN + FCN - 1) / FCN)    // 157 fc blocks
#define DEGCAP 512

static __device__ __forceinline__ unsigned short f2bf(float f) {
    unsigned u = __float_as_uint(f);
    unsigned r = (u + 0x7FFFu + ((u >> 16) & 1u)) >> 16;   // RNE
    return (unsigned short)r;
}
static __device__ __forceinline__ float bfhi(unsigned u) { return __uint_as_float(u & 0xFFFF0000u); }
static __device__ __forceinline__ float bflo(unsigned u) { return __uint_as_float(u << 16); }

// ---------------------------------------------------------------------------
// K1: blocks 0..63 -> LDS histogram of dst ; blocks 64..220 -> fc.
// fc reads W rows DIRECTLY (no transpose): W[j][k..k+3] float4, L1-hot.
// ---------------------------------------------------------------------------
__global__ __launch_bounds__(512, 2) void histfc_kernel(
    const int* __restrict__ dst, int* __restrict__ bh,
    const float* __restrict__ h, const float* __restrict__ W,
    const float* __restrict__ Wa, unsigned short* __restrict__ zb,
    float* __restrict__ e)
{
    __shared__ int smem[10240];                    // 40 KB, aliased per role
    const int bid = blockIdx.x, t = threadIdx.x;

    if (bid < HNB) {
        // ---- histogram ----
        int* lh = smem;
        for (int v = t; v < NN; v += 512) lh[v] = 0;
        __syncthreads();
        const int4* d4 = (const int4*)(dst + bid * HEPB);
        for (int i = t; i < HEPB / 4; i += 512) {
            int4 d = d4[i];
            atomicAdd(&lh[d.x], 1); atomicAdd(&lh[d.y], 1);
            atomicAdd(&lh[d.z], 1); atomicAdd(&lh[d.w], 1);
        }
        __syncthreads();
        for (int v = t; v < NN; v += 512) bh[(size_t)bid * NN + v] = lh[v];
    } else {
        // ---- fc: z(bf16) = h @ W^T, e = z . a_src ----
        float* hs = (float*)smem;                  // [FCN][DIM] = 32 KB
        const int jl = t & 31, jq = jl * 4;
        const int ng = t >> 5;                     // 0..15, 4 nodes each
        const int i0 = (bid - HNB) * FCN;

        const float4* h4 = (const float4*)h;
        float4* hs4 = (float4*)hs;
        for (int u = t; u < FCN * 32; u += 512) {
            int gi = i0 + (u >> 5);
            hs4[u] = (gi < NN) ? h4[(size_t)gi * 32 + (u & 31)]
                               : make_float4(0.f, 0.f, 0.f, 0.f);
        }
        __syncthreads();

        const float4* W4 = (const float4*)W;
        float acc[4][4] = {};
        for (int kq = 0; kq < 32; ++kq) {
            float4 wrow[4];
            #pragma unroll
            for (int jm = 0; jm < 4; ++jm)
                wrow[jm] = W4[(size_t)(jq + jm) * 32 + kq];   // W[j][4kq..4kq+3]
            #pragma unroll
            for (int m = 0; m < 4; ++m) {
                float4 hv = *(const float4*)&hs[(4 * ng + m) * DIM + 4 * kq];
                #pragma unroll
                for (int jm = 0; jm < 4; ++jm)
                    acc[m][jm] += hv.x * wrow[jm].x + hv.y * wrow[jm].y
                                + hv.z * wrow[jm].z + hv.w * wrow[jm].w;
            }
        }

        const float a0 = Wa[jq], a1 = Wa[jq + 1], a2 = Wa[jq + 2], a3 = Wa[jq + 3];
        #pragma unroll
        for (int m = 0; m < 4; ++m) {
            int gi = i0 + 4 * ng + m;
            float ep = acc[m][0] * a0 + acc[m][1] * a1 + acc[m][2] * a2 + acc[m][3] * a3;
            #pragma unroll
            for (int o = 16; o > 0; o >>= 1) ep += __shfl_xor(ep, o, 64);
            if (gi < NN) {
                ushort4 zo;
                zo.x = f2bf(acc[m][0]); zo.y = f2bf(acc[m][1]);
                zo.z = f2bf(acc[m][2]); zo.w = f2bf(acc[m][3]);
                *(ushort4*)&zb[(size_t)gi * DIM + jq] = zo;
                if (jl == 0) e[gi] = ep;
            }
        }
    }
}

// ---------------------------------------------------------------------------
// K2: one WAVE per column v: lane l holds bh[l][v]; 6-shuffle exclusive scan
// replaces the 64-deep dependent-load chain. cnt[v] = column total.
// ---------------------------------------------------------------------------
__global__ __launch_bounds__(512) void colscan_kernel(
    int* __restrict__ bh, int* __restrict__ cnt)
{
    const int lane = threadIdx.x & 63, w = threadIdx.x >> 6;
    const int v = blockIdx.x * 8 + w;              // 1250 blocks * 8 waves = 10000
    int c = bh[(size_t)lane * NN + v];
    int x = c;
    #pragma unroll
    for (int o = 1; o <= 32; o <<= 1) {
        int y = __shfl_up(x, o, 64);
        if (lane >= o) x += y;
    }
    bh[(size_t)lane * NN + v] = x - c;             // exclusive prefix
    if (lane == 63) cnt[v] = x;
}

// ---------------------------------------------------------------------------
// K3: exclusive scan cnt -> offs (1 block, 1024 thr, wave-shuffle)
// ---------------------------------------------------------------------------
__global__ __launch_bounds__(1024) void scan_kernel(
    const int* __restrict__ cnt, int* __restrict__ offs, int n)
{
    __shared__ int wsum[16];
    const int t = threadIdx.x, lane = t & 63, wid = t >> 6;
    constexpr int C = 10;
    int loc[C];
    int base = t * C, s = 0;
    #pragma unroll
    for (int j = 0; j < C; ++j) {
        int idx = base + j;
        int v = (idx < n) ? cnt[idx] : 0;
        loc[j] = s; s += v;
    }
    int x = s;
    #pragma unroll
    for (int off = 1; off <= 32; off <<= 1) {
        int y = __shfl_up(x, off, 64);
        if (lane >= off) x += y;
    }
    if (lane == 63) wsum[wid] = x;
    __syncthreads();
    if (t < 16) {
        int w = wsum[t];
        #pragma unroll
        for (int off = 1; off <= 8; off <<= 1) {
            int y = __shfl_up(w, off, 64);
            if (t >= off) w += y;
        }
        wsum[t] = w;
    }
    __syncthreads();
    int wbase = (wid == 0) ? 0 : wsum[wid - 1];
    int excl = wbase + (x - s);
    #pragma unroll
    for (int j = 0; j < C; ++j) {
        int idx = base + j;
        if (idx < n) offs[idx] = excl + loc[j];
    }
    if (t == 0) offs[n] = wsum[15];
}

// ---------------------------------------------------------------------------
// K4: LDS-ranked scatter. esrc[offs[d] + bh[b][d] + local_rank] = src.
// ---------------------------------------------------------------------------
__global__ __launch_bounds__(512) void scatter_kernel(
    const int* __restrict__ src, const int* __restrict__ dst,
    const int* __restrict__ base, const int* __restrict__ offs,
    int* __restrict__ esrc)
{
    __shared__ int lcur[NN];
    const int b = blockIdx.x, t = threadIdx.x;
    for (int v = t; v < NN; v += 512) lcur[v] = 0;
    __syncthreads();
    const int4* d4 = (const int4*)(dst + b * HEPB);
    const int4* s4 = (const int4*)(src + b * HEPB);
    const int* brow = base + (size_t)b * NN;
    for (int i = t; i < HEPB / 4; i += 512) {
        int4 d = d4[i]; int4 s = s4[i];
        int lp;
        lp = atomicAdd(&lcur[d.x], 1); esrc[offs[d.x] + brow[d.x] + lp] = s.x;
        lp = atomicAdd(&lcur[d.y], 1); esrc[offs[d.y] + brow[d.y] + lp] = s.y;
        lp = atomicAdd(&lcur[d.z], 1); esrc[offs[d.z] + brow[d.z] + lp] = s.z;
        lp = atomicAdd(&lcur[d.w], 1); esrc[offs[d.w] + brow[d.w] + lp] = s.w;
    }
}

// ---------------------------------------------------------------------------
// K5: softmax + aggregate. 1 wave per node; thread t owns dims {2t, 2t+1}.
// e-values cached in LDS during pass 1 (pass 2 avoids the 2nd random gather).
// ---------------------------------------------------------------------------
__global__ __launch_bounds__(64) void agg64_kernel(
    const int* __restrict__ offs, const int* __restrict__ esrc,
    const float* __restrict__ e, const unsigned* __restrict__ zb32,
    float* __restrict__ out)
{
    __shared__ int   es[DEGCAP];
    __shared__ float ew[DEGCAP];
    const int v = blockIdx.x, t = threadIdx.x;
    const int beg = offs[v], end = offs[v + 1];
    const int deg = end - beg;

    if (deg <= DEGCAP) {
        float lm = -3.4e38f;
        for (int i = t; i < deg; i += 64) {
            int s = esrc[beg + i];
            float ev = e[s];
            es[i] = s; ew[i] = ev;
            lm = fmaxf(lm, ev);
        }
        #pragma unroll
        for (int o = 32; o > 0; o >>= 1) lm = fmaxf(lm, __shfl_xor(lm, o, 64));

        float ls = 0.f;
        for (int i = t; i < deg; i += 64) {
            float w = __expf(ew[i] - lm);          // same-lane LDS RAW
            ew[i] = w; ls += w;
        }
        #pragma unroll
        for (int o = 32; o > 0; o >>= 1) ls += __shfl_xor(ls, o, 64);
        const float inv = (ls > 0.f) ? (1.f / ls) : 0.f;
        __syncthreads();                           // es/ew cross-lane visible

        float a0 = 0.f, a1 = 0.f, a2 = 0.f, a3 = 0.f;
        int i = 0;
        for (; i + 3 < deg; i += 4) {
            unsigned u0 = zb32[(size_t)es[i]     * 64 + t];
            unsigned u1 = zb32[(size_t)es[i + 1] * 64 + t];
            unsigned u2 = zb32[(size_t)es[i + 2] * 64 + t];
            unsigned u3 = zb32[(size_t)es[i + 3] * 64 + t];
            a0 += ew[i]     * bflo(u0); a1 += ew[i]     * bfhi(u0);
            a2 += ew[i + 1] * bflo(u1); a3 += ew[i + 1] * bfhi(u1);
            a0 += ew[i + 2] * bflo(u2); a1 += ew[i + 2] * bfhi(u2);
            a2 += ew[i + 3] * bflo(u3); a3 += ew[i + 3] * bfhi(u3);
        }
        for (; i < deg; ++i) {
            unsigned u = zb32[(size_t)es[i] * 64 + t];
            a0 += ew[i] * bflo(u); a1 += ew[i] * bfhi(u);
        }
        float2 r;
        r.x = (a0 + a2) * inv;
        r.y = (a1 + a3) * inv;
        *(float2*)&out[(size_t)v * DIM + 2 * t] = r;
    } else {
        float lm = -3.4e38f;
        for (int i = beg + t; i < end; i += 64) lm = fmaxf(lm, e[esrc[i]]);
        #pragma unroll
        for (int o = 32; o > 0; o >>= 1) lm = fmaxf(lm, __shfl_xor(lm, o, 64));
        float ls = 0.f;
        for (int i = beg + t; i < end; i += 64) ls += __expf(e[esrc[i]] - lm);
        #pragma unroll
        for (int o = 32; o > 0; o >>= 1) ls += __shfl_xor(ls, o, 64);
        const float inv = (ls > 0.f) ? (1.f / ls) : 0.f;
        float a0 = 0.f, a1 = 0.f;
        for (int i = beg; i < end; ++i) {
            int s = esrc[i];
            float w = __expf(e[s] - lm);
            unsigned u = zb32[(size_t)s * 64 + t];
            a0 += w * bflo(u); a1 += w * bfhi(u);
        }
        float2 r;
        r.x = a0 * inv;
        r.y = a1 * inv;
        *(float2*)&out[(size_t)v * DIM + 2 * t] = r;
    }
}

// ---------------------------------------------------------------------------
extern "C" void kernel_launch(void* const* d_in, const int* in_sizes, int n_in,
                              void* d_out, int out_size, void* d_ws, size_t ws_size,
                              hipStream_t stream)
{
    const float* h     = (const float*)d_in[0];
    const int*   src   = (const int*)d_in[1];
    const int*   dst   = (const int*)d_in[2];
    const float* Wfc   = (const float*)d_in[3];
    const float* Wattn = (const float*)d_in[4];
    float* out = (float*)d_out;

    // workspace (~10.5 MB), all segments 16B-aligned
    unsigned short* zb   = (unsigned short*)d_ws;         // NN*DIM ushort (2.56 MB)
    float*          e    = (float*)(zb + (size_t)NN * DIM + 16);
    int*            cnt  = (int*)(e + 10016);
    int*            offs = cnt + 10016;
    int*            bh   = offs + 10016;                  // HNB*NN int (2.56 MB)
    int*            esrc = bh + (size_t)HNB * NN;         // NE int (2.56 MB)

    histfc_kernel<<<HNB + FCB, 512, 0, stream>>>(dst, bh, h, Wfc, Wattn, zb, e);
    colscan_kernel<<<NN / 8, 512, 0, stream>>>(bh, cnt);
    scan_kernel<<<1, 1024, 0, stream>>>(cnt, offs, NN);
    scatter_kernel<<<HNB, 512, 0, stream>>>(src, dst, bh, offs, esrc);
    agg64_kernel<<<NN, 64, 0, stream>>>(offs, esrc, e, (const unsigned*)zb, out);
}

// Round 7
// 67.213 us; speedup vs baseline: 5.6609x; 1.4203x over previous
//
#include <hip/hip_runtime.h>

#define NN 10000
#define NE 640000
#define DIM 128
#define HNB 64                        // hist/scatter blocks
#define HEPB 10000                    // edges per hist/scatter block
#define FCN 64                        // nodes per fc block
#define FCB ((NN + FCN - 1) / FCN)    // 157 fc blocks
#define DEGCAP 512

static __device__ __forceinline__ unsigned short f2bf(float f) {
    unsigned u = __float_as_uint(f);
    unsigned r = (u + 0x7FFFu + ((u >> 16) & 1u)) >> 16;   // RNE
    return (unsigned short)r;
}
static __device__ __forceinline__ float bfhi(unsigned u) { return __uint_as_float(u & 0xFFFF0000u); }
static __device__ __forceinline__ float bflo(unsigned u) { return __uint_as_float(u << 16); }

// ---------------------------------------------------------------------------
// K1: LDS histogram of dst (64 blocks x 512 thr) + fused W transpose.
// ---------------------------------------------------------------------------
__global__ __launch_bounds__(512) void histT_kernel(
    const int* __restrict__ dst, int* __restrict__ bh,
    const float* __restrict__ W, float* __restrict__ Wt)
{
    __shared__ int lh[NN];
    const int b = blockIdx.x, t = threadIdx.x;
    for (int v = t; v < NN; v += 512) lh[v] = 0;
    if (t < 256) {                                  // 64*256 = 16384 = |W|
        int idx = b * 256 + t;
        Wt[(idx & 127) * DIM + (idx >> 7)] = W[idx];
    }
    __syncthreads();
    const int4* d4 = (const int4*)(dst + b * HEPB);
    for (int i = t; i < HEPB / 4; i += 512) {
        int4 d = d4[i];
        atomicAdd(&lh[d.x], 1); atomicAdd(&lh[d.y], 1);
        atomicAdd(&lh[d.z], 1); atomicAdd(&lh[d.w], 1);
    }
    __syncthreads();
    for (int v = t; v < NN; v += 512) bh[(size_t)b * NN + v] = lh[v];
}

// ---------------------------------------------------------------------------
// K2: one WAVE per column v of bh: 6-shuffle exclusive scan down the column.
// ---------------------------------------------------------------------------
__global__ __launch_bounds__(512) void colscan_kernel(
    int* __restrict__ bh, int* __restrict__ cnt)
{
    const int lane = threadIdx.x & 63, w = threadIdx.x >> 6;
    const int v = blockIdx.x * 8 + w;              // 1250 blocks * 8 waves
    int c = bh[(size_t)lane * NN + v];
    int x = c;
    #pragma unroll
    for (int o = 1; o <= 32; o <<= 1) {
        int y = __shfl_up(x, o, 64);
        if (lane >= o) x += y;
    }
    bh[(size_t)lane * NN + v] = x - c;             // exclusive prefix
    if (lane == 63) cnt[v] = x;
}

// ---------------------------------------------------------------------------
// K3: exclusive scan cnt -> offs (1 block, wave-shuffle)
// ---------------------------------------------------------------------------
__global__ __launch_bounds__(1024) void scan_kernel(
    const int* __restrict__ cnt, int* __restrict__ offs, int n)
{
    __shared__ int wsum[16];
    const int t = threadIdx.x, lane = t & 63, wid = t >> 6;
    constexpr int C = 10;
    int loc[C];
    int base = t * C, s = 0;
    #pragma unroll
    for (int j = 0; j < C; ++j) {
        int idx = base + j;
        int v = (idx < n) ? cnt[idx] : 0;
        loc[j] = s; s += v;
    }
    int x = s;
    #pragma unroll
    for (int off = 1; off <= 32; off <<= 1) {
        int y = __shfl_up(x, off, 64);
        if (lane >= off) x += y;
    }
    if (lane == 63) wsum[wid] = x;
    __syncthreads();
    if (t < 16) {
        int w = wsum[t];
        #pragma unroll
        for (int off = 1; off <= 8; off <<= 1) {
            int y = __shfl_up(w, off, 64);
            if (t >= off) w += y;
        }
        wsum[t] = w;
    }
    __syncthreads();
    int wbase = (wid == 0) ? 0 : wsum[wid - 1];
    int excl = wbase + (x - s);
    #pragma unroll
    for (int j = 0; j < C; ++j) {
        int idx = base + j;
        if (idx < n) offs[idx] = excl + loc[j];
    }
    if (t == 0) offs[n] = wsum[15];
}

// ---------------------------------------------------------------------------
// K4: blocks 0..63 scatter ; blocks 64..220 fc (coalesced Wt register tiles).
// fc hidden under scatter: its outputs (zb, e) are needed only by K5.
// ---------------------------------------------------------------------------
__global__ __launch_bounds__(512, 2) void scatfc_kernel(
    const int* __restrict__ src, const int* __restrict__ dst,
    const int* __restrict__ base, const int* __restrict__ offs,
    int* __restrict__ esrc,
    const float* __restrict__ h, const float* __restrict__ Wt,
    const float* __restrict__ Wa, unsigned short* __restrict__ zb,
    float* __restrict__ e)
{
    __shared__ int smem[10240];                    // 40 KB, aliased per role
    const int bid = blockIdx.x, t = threadIdx.x;

    if (bid < HNB) {
        // ---- LDS-ranked scatter ----
        int* lcur = smem;
        for (int v = t; v < NN; v += 512) lcur[v] = 0;
        __syncthreads();
        const int4* d4 = (const int4*)(dst + bid * HEPB);
        const int4* s4 = (const int4*)(src + bid * HEPB);
        const int* brow = base + (size_t)bid * NN;
        for (int i = t; i < HEPB / 4; i += 512) {
            int4 d = d4[i]; int4 s = s4[i];
            int lp;
            lp = atomicAdd(&lcur[d.x], 1); esrc[offs[d.x] + brow[d.x] + lp] = s.x;
            lp = atomicAdd(&lcur[d.y], 1); esrc[offs[d.y] + brow[d.y] + lp] = s.y;
            lp = atomicAdd(&lcur[d.z], 1); esrc[offs[d.z] + brow[d.z] + lp] = s.z;
            lp = atomicAdd(&lcur[d.w], 1); esrc[offs[d.w] + brow[d.w] + lp] = s.w;
        }
    } else {
        // ---- fc: z(bf16) = h @ W^T, e = z . a_src ----
        float* hs = (float*)smem;                  // [FCN][DIM] = 32 KB
        const int jl = t & 31, jq = jl * 4;
        const int ng = t >> 5;                     // 0..15, 4 nodes each
        const int i0 = (bid - HNB) * FCN;

        const float4* h4 = (const float4*)h;
        float4* hs4 = (float4*)hs;
        for (int u = t; u < FCN * 32; u += 512) {
            int gi = i0 + (u >> 5);
            hs4[u] = (gi < NN) ? h4[(size_t)gi * 32 + (u & 31)]
                               : make_float4(0.f, 0.f, 0.f, 0.f);
        }
        __syncthreads();

        float acc[4][4] = {};
        for (int k = 0; k < DIM; k += 4) {
            float4 wv[4];
            #pragma unroll
            for (int kk = 0; kk < 4; ++kk)
                wv[kk] = *(const float4*)&Wt[(k + kk) * DIM + jq];  // coalesced
            const float* wf = (const float*)wv;
            #pragma unroll
            for (int m = 0; m < 4; ++m) {
                float4 hv = *(const float4*)&hs[(4 * ng + m) * DIM + k];
                float hvf[4] = {hv.x, hv.y, hv.z, hv.w};
                #pragma unroll
                for (int kk = 0; kk < 4; ++kk)
                    #pragma unroll
                    for (int jm = 0; jm < 4; ++jm)
                        acc[m][jm] += hvf[kk] * wf[kk * 4 + jm];
            }
        }

        const float a0 = Wa[jq], a1 = Wa[jq + 1], a2 = Wa[jq + 2], a3 = Wa[jq + 3];
        #pragma unroll
        for (int m = 0; m < 4; ++m) {
            int gi = i0 + 4 * ng + m;
            float ep = acc[m][0] * a0 + acc[m][1] * a1 + acc[m][2] * a2 + acc[m][3] * a3;
            #pragma unroll
            for (int o = 16; o > 0; o >>= 1) ep += __shfl_xor(ep, o, 64);
            if (gi < NN) {
                ushort4 zo;
                zo.x = f2bf(acc[m][0]); zo.y = f2bf(acc[m][1]);
                zo.z = f2bf(acc[m][2]); zo.w = f2bf(acc[m][3]);
                *(ushort4*)&zb[(size_t)gi * DIM + jq] = zo;
                if (jl == 0) e[gi] = ep;
            }
        }
    }
}

// ---------------------------------------------------------------------------
// K5: softmax + aggregate. 1 wave per node; thread t owns dims {2t, 2t+1}.
// ---------------------------------------------------------------------------
__global__ __launch_bounds__(64) void agg64_kernel(
    const int* __restrict__ offs, const int* __restrict__ esrc,
    const float* __restrict__ e, const unsigned* __restrict__ zb32,
    float* __restrict__ out)
{
    __shared__ int   es[DEGCAP];
    __shared__ float ew[DEGCAP];
    const int v = blockIdx.x, t = threadIdx.x;
    const int beg = offs[v], end = offs[v + 1];
    const int deg = end - beg;

    if (deg <= DEGCAP) {
        float lm = -3.4e38f;
        for (int i = t; i < deg; i += 64) {
            int s = esrc[beg + i];
            float ev = e[s];
            es[i] = s; ew[i] = ev;
            lm = fmaxf(lm, ev);
        }
        #pragma unroll
        for (int o = 32; o > 0; o >>= 1) lm = fmaxf(lm, __shfl_xor(lm, o, 64));

        float ls = 0.f;
        for (int i = t; i < deg; i += 64) {
            float w = __expf(ew[i] - lm);          // same-lane LDS RAW
            ew[i] = w; ls += w;
        }
        #pragma unroll
        for (int o = 32; o > 0; o >>= 1) ls += __shfl_xor(ls, o, 64);
        const float inv = (ls > 0.f) ? (1.f / ls) : 0.f;
        __syncthreads();                           // es/ew cross-lane visible

        float a0 = 0.f, a1 = 0.f, a2 = 0.f, a3 = 0.f;
        int i = 0;
        for (; i + 3 < deg; i += 4) {
            unsigned u0 = zb32[(size_t)es[i]     * 64 + t];
            unsigned u1 = zb32[(size_t)es[i + 1] * 64 + t];
            unsigned u2 = zb32[(size_t)es[i + 2] * 64 + t];
            unsigned u3 = zb32[(size_t)es[i + 3] * 64 + t];
            a0 += ew[i]     * bflo(u0); a1 += ew[i]     * bfhi(u0);
            a2 += ew[i + 1] * bflo(u1); a3 += ew[i + 1] * bfhi(u1);
            a0 += ew[i + 2] * bflo(u2); a1 += ew[i + 2] * bfhi(u2);
            a2 += ew[i + 3] * bflo(u3); a3 += ew[i + 3] * bfhi(u3);
        }
        for (; i < deg; ++i) {
            unsigned u = zb32[(size_t)es[i] * 64 + t];
            a0 += ew[i] * bflo(u); a1 += ew[i] * bfhi(u);
        }
        float2 r;
        r.x = (a0 + a2) * inv;
        r.y = (a1 + a3) * inv;
        *(float2*)&out[(size_t)v * DIM + 2 * t] = r;
    } else {
        float lm = -3.4e38f;
        for (int i = beg + t; i < end; i += 64) lm = fmaxf(lm, e[esrc[i]]);
        #pragma unroll
        for (int o = 32; o > 0; o >>= 1) lm = fmaxf(lm, __shfl_xor(lm, o, 64));
        float ls = 0.f;
        for (int i = beg + t; i < end; i += 64) ls += __expf(e[esrc[i]] - lm);
        #pragma unroll
        for (int o = 32; o > 0; o >>= 1) ls += __shfl_xor(ls, o, 64);
        const float inv = (ls > 0.f) ? (1.f / ls) : 0.f;
        float a0 = 0.f, a1 = 0.f;
        for (int i = beg; i < end; ++i) {
            int s = esrc[i];
            float w = __expf(e[s] - lm);
            unsigned u = zb32[(size_t)s * 64 + t];
            a0 += w * bflo(u); a1 += w * bfhi(u);
        }
        float2 r;
        r.x = a0 * inv;
        r.y = a1 * inv;
        *(float2*)&out[(size_t)v * DIM + 2 * t] = r;
    }
}

// ---------------------------------------------------------------------------
extern "C" void kernel_launch(void* const* d_in, const int* in_sizes, int n_in,
                              void* d_out, int out_size, void* d_ws, size_t ws_size,
                              hipStream_t stream)
{
    const float* h     = (const float*)d_in[0];
    const int*   src   = (const int*)d_in[1];
    const int*   dst   = (const int*)d_in[2];
    const float* Wfc   = (const float*)d_in[3];
    const float* Wattn = (const float*)d_in[4];
    float* out = (float*)d_out;

    // workspace (~10.6 MB), 16B-aligned segments
    unsigned short* zb   = (unsigned short*)d_ws;         // NN*DIM ushort
    float*          e    = (float*)(zb + (size_t)NN * DIM + 16);
    int*            cnt  = (int*)(e + 10016);
    int*            offs = cnt + 10016;
    float*          Wt   = (float*)(offs + 10016);        // 16,384 f32
    int*            bh   = (int*)(Wt + 16384);            // HNB*NN int
    int*            esrc = bh + (size_t)HNB * NN;         // NE int

    histT_kernel<<<HNB, 512, 0, stream>>>(dst, bh, Wfc, Wt);
    colscan_kernel<<<NN / 8, 512, 0, stream>>>(bh, cnt);
    scan_kernel<<<1, 1024, 0, stream>>>(cnt, offs, NN);
    scatfc_kernel<<<HNB + FCB, 512, 0, stream>>>(src, dst, bh, offs, esrc,
                                                 h, Wt, Wattn, zb, e);
    agg64_kernel<<<NN, 64, 0, stream>>>(offs, esrc, e, (const unsigned*)zb, out);
}